// Round 1
// baseline (2875.827 us; speedup 1.0000x reference)
//
#include <hip/hip_runtime.h>
#include <math.h>

#define N_NODES 50000
#define N_EDGES 800000
#define EMBED 256
#define HID 128
#define OUTD 12
#define N_TGT 4096

// ---------------- degree / norm ----------------
__global__ void k_deg_init(float* deg, int n) {
    int i = blockIdx.x * 256 + threadIdx.x;
    if (i < n) deg[i] = 1.0f;  // self loop
}

__global__ void k_deg_edges(const int* __restrict__ dst, float* deg, int nE) {
    int i = blockIdx.x * 256 + threadIdx.x;
    if (i < nE) atomicAdd(&deg[dst[i]], 1.0f);
}

__global__ void k_dinv(float* deg, int n) {
    int i = blockIdx.x * 256 + threadIdx.x;
    if (i < n) deg[i] = rsqrtf(deg[i]);  // deg >= 1 always (self loop)
}

// ---------------- tiled f32 GEMM: H[n][128] = X[n][K] @ W[K][128] ----------------
template <int K>
__global__ __launch_bounds__(128) void k_gemm(const float* __restrict__ X,
                                              const float* __restrict__ W,
                                              float* __restrict__ H, int n) {
    __shared__ float As[32][68];   // transposed x tile: As[k][row], padded stride
    __shared__ float Bs[32][132];  // Bs[k][col], padded stride (mult of 4)
    const int tid = threadIdx.x;
    const int row0 = blockIdx.x * 64;
    const int ty = tid >> 4;   // 0..7  (row group of 8)
    const int tx = tid & 15;   // 0..15 (col group of 8)
    float acc[8][8] = {};
    for (int k0 = 0; k0 < K; k0 += 32) {
        // load A tile 64x32 (transposed into LDS)
#pragma unroll
        for (int i = 0; i < 4; ++i) {
            int f = tid + i * 128;          // 0..511 float4 slots
            int r = f >> 3, k4 = f & 7;
            float4 v = make_float4(0.f, 0.f, 0.f, 0.f);
            if (row0 + r < n)
                v = *(const float4*)&X[(size_t)(row0 + r) * K + k0 + k4 * 4];
            As[k4 * 4 + 0][r] = v.x;
            As[k4 * 4 + 1][r] = v.y;
            As[k4 * 4 + 2][r] = v.z;
            As[k4 * 4 + 3][r] = v.w;
        }
        // load B tile 32x128
#pragma unroll
        for (int i = 0; i < 8; ++i) {
            int f = tid + i * 128;          // 0..1023 float4 slots
            int kk = f >> 5, c4 = f & 31;
            *(float4*)&Bs[kk][c4 * 4] = *(const float4*)&W[(size_t)(k0 + kk) * 128 + c4 * 4];
        }
        __syncthreads();
#pragma unroll
        for (int k = 0; k < 32; ++k) {
            float4 a0 = *(const float4*)&As[k][ty * 8];
            float4 a1 = *(const float4*)&As[k][ty * 8 + 4];
            float4 b0 = *(const float4*)&Bs[k][tx * 8];
            float4 b1 = *(const float4*)&Bs[k][tx * 8 + 4];
            float a[8] = {a0.x, a0.y, a0.z, a0.w, a1.x, a1.y, a1.z, a1.w};
            float b[8] = {b0.x, b0.y, b0.z, b0.w, b1.x, b1.y, b1.z, b1.w};
#pragma unroll
            for (int i = 0; i < 8; ++i)
#pragma unroll
                for (int j = 0; j < 8; ++j) acc[i][j] = fmaf(a[i], b[j], acc[i][j]);
        }
        __syncthreads();
    }
#pragma unroll
    for (int i = 0; i < 8; ++i) {
        int r = row0 + ty * 8 + i;
        if (r < n) {
            *(float4*)&H[(size_t)r * 128 + tx * 8] =
                make_float4(acc[i][0], acc[i][1], acc[i][2], acc[i][3]);
            *(float4*)&H[(size_t)r * 128 + tx * 8 + 4] =
                make_float4(acc[i][4], acc[i][5], acc[i][6], acc[i][7]);
        }
    }
}

// ---------------- aggregation ----------------
// self-loop init: agg[v] = h[v] * dinv[v]^2
__global__ void k_agg_init(const float* __restrict__ h, const float* __restrict__ dinv,
                           float* __restrict__ agg, int n) {
    int i4 = blockIdx.x * 256 + threadIdx.x;       // float4 index
    int total = n * (HID / 4);
    if (i4 >= total) return;
    int node = i4 >> 5;                            // 32 float4 per row
    float s = dinv[node];
    s *= s;
    float4 v = *(const float4*)&h[(size_t)i4 * 4];
    v.x *= s; v.y *= s; v.z *= s; v.w *= s;
    *(float4*)&agg[(size_t)i4 * 4] = v;
}

// scatter-add over edges: 32 lanes per edge, float4 gather + 4 scalar atomics
__global__ void k_agg_edges(const float* __restrict__ h, const int* __restrict__ src,
                            const int* __restrict__ dst, const float* __restrict__ dinv,
                            float* __restrict__ agg, int nE) {
    int t = blockIdx.x * 256 + threadIdx.x;
    int e = t >> 5;
    int lane = t & 31;
    if (e >= nE) return;
    int s = src[e], d = dst[e];
    float norm = dinv[s] * dinv[d];
    float4 v = *(const float4*)&h[(size_t)s * HID + lane * 4];
    float* out = &agg[(size_t)d * HID + lane * 4];
    atomicAdd(out + 0, v.x * norm);
    atomicAdd(out + 1, v.y * norm);
    atomicAdd(out + 2, v.z * norm);
    atomicAdd(out + 3, v.w * norm);
}

// agg = relu(agg + b), in place
__global__ void k_bias_relu(float* __restrict__ agg, const float* __restrict__ b, int n) {
    int i4 = blockIdx.x * 256 + threadIdx.x;
    int total = n * (HID / 4);
    if (i4 >= total) return;
    int c4 = (i4 & 31) * 4;
    float4 bv = *(const float4*)&b[c4];
    float4 v = *(float4*)&agg[(size_t)i4 * 4];
    v.x = fmaxf(v.x + bv.x, 0.f);
    v.y = fmaxf(v.y + bv.y, 0.f);
    v.z = fmaxf(v.z + bv.z, 0.f);
    v.w = fmaxf(v.w + bv.w, 0.f);
    *(float4*)&agg[(size_t)i4 * 4] = v;
}

// ---------------- final readout: pred[t] = h[mask[t]] @ Wr + br ----------------
__global__ void k_final(const float* __restrict__ h, const int* __restrict__ mask,
                        const float* __restrict__ Wr, const float* __restrict__ br,
                        float* __restrict__ out) {
    int t = blockIdx.x;        // 4096
    int lane = threadIdx.x;    // 64
    int node = mask[t];
    float2 hv = *(const float2*)&h[(size_t)node * HID + lane * 2];
#pragma unroll
    for (int j = 0; j < OUTD; ++j) {
        float p = hv.x * Wr[(lane * 2) * OUTD + j] + hv.y * Wr[(lane * 2 + 1) * OUTD + j];
#pragma unroll
        for (int off = 32; off > 0; off >>= 1) p += __shfl_down(p, off);
        if (lane == 0) out[t * OUTD + j] = p + br[j];
    }
}

extern "C" void kernel_launch(void* const* d_in, const int* in_sizes, int n_in,
                              void* d_out, int out_size, void* d_ws, size_t ws_size,
                              hipStream_t stream) {
    const float* x   = (const float*)d_in[0];
    const int*   ei  = (const int*)d_in[1];         // [2][800000], int32
    const int*   tm  = (const int*)d_in[2];         // [4096]
    const float* W1  = (const float*)d_in[3];
    const float* b1  = (const float*)d_in[4];
    const float* W2  = (const float*)d_in[5];
    const float* b2  = (const float*)d_in[6];
    const float* Wr  = (const float*)d_in[7];
    const float* br  = (const float*)d_in[8];
    float* out = (float*)d_out;

    const int* e_src = ei;
    const int* e_dst = ei + N_EDGES;

    char* ws = (char*)d_ws;
    float* dinv = (float*)ws;                                 // 50000 f32
    float* bufA = (float*)(ws + (1 << 18));                   // 25.6 MB
    float* bufB = (float*)(ws + (1 << 18) + (size_t)N_NODES * HID * 4);

    const int NB_N   = (N_NODES + 255) / 256;
    const int NB_E   = (N_EDGES + 255) / 256;
    const int NB_EL  = (N_NODES * (HID / 4) + 255) / 256;     // elementwise float4
    const int NB_AGG = (N_EDGES * 32 + 255) / 256;
    const int NB_G   = (N_NODES + 63) / 64;

    // degree + norm
    k_deg_init<<<NB_N, 256, 0, stream>>>(dinv, N_NODES);
    k_deg_edges<<<NB_E, 256, 0, stream>>>(e_dst, dinv, N_EDGES);
    k_dinv<<<NB_N, 256, 0, stream>>>(dinv, N_NODES);

    // layer 1
    k_gemm<EMBED><<<NB_G, 128, 0, stream>>>(x, W1, bufA, N_NODES);
    k_agg_init<<<NB_EL, 256, 0, stream>>>(bufA, dinv, bufB, N_NODES);
    k_agg_edges<<<NB_AGG, 256, 0, stream>>>(bufA, e_src, e_dst, dinv, bufB, N_EDGES);
    k_bias_relu<<<NB_EL, 256, 0, stream>>>(bufB, b1, N_NODES);

    // layer 2
    k_gemm<HID><<<NB_G, 128, 0, stream>>>(bufB, W2, bufA, N_NODES);
    k_agg_init<<<NB_EL, 256, 0, stream>>>(bufA, dinv, bufB, N_NODES);
    k_agg_edges<<<NB_AGG, 256, 0, stream>>>(bufA, e_src, e_dst, dinv, bufB, N_EDGES);
    k_bias_relu<<<NB_EL, 256, 0, stream>>>(bufB, b2, N_NODES);

    // readout
    k_final<<<N_TGT, 64, 0, stream>>>(bufB, tm, Wr, br, out);
}

// Round 2
// 404.323 us; speedup vs baseline: 7.1127x; 7.1127x over previous
//
#include <hip/hip_runtime.h>
#include <math.h>

#define N_NODES 50000
#define N_EDGES 800000
#define EMBED 256
#define HID 128
#define OUTD 12
#define N_TGT 4096

// ---------------- CSR build ----------------
__global__ void k_hist(const int* __restrict__ dst, int* __restrict__ counts, int nE) {
    int i = blockIdx.x * 256 + threadIdx.x;
    if (i < nE) atomicAdd(&counts[dst[i]], 1);
}

// single-block exclusive scan of counts[N_NODES] -> rowptr[N_NODES]
__global__ __launch_bounds__(1024) void k_scan(const int* __restrict__ counts,
                                               int* __restrict__ rowptr) {
    __shared__ int sums[1024];
    const int tid = threadIdx.x;
    const int CH = (N_NODES + 1023) / 1024;  // 49
    int start = tid * CH;
    int end = min(start + CH, N_NODES);
    int local = 0;
    for (int i = start; i < end; ++i) local += counts[i];
    sums[tid] = local;
    __syncthreads();
    for (int off = 1; off < 1024; off <<= 1) {
        int v = (tid >= off) ? sums[tid - off] : 0;
        __syncthreads();
        sums[tid] += v;
        __syncthreads();
    }
    int prefix = sums[tid] - local;  // exclusive prefix
    for (int i = start; i < end; ++i) {
        rowptr[i] = prefix;
        prefix += counts[i];
    }
}

__global__ void k_fill(const int* __restrict__ src, const int* __restrict__ dst,
                       int* __restrict__ cursor, int* __restrict__ col, int nE) {
    int i = blockIdx.x * 256 + threadIdx.x;
    if (i < nE) {
        int pos = atomicAdd(&cursor[dst[i]], 1);
        col[pos] = src[i];
    }
}

__global__ void k_dinv(const int* __restrict__ counts, float* __restrict__ dinv, int n) {
    int i = blockIdx.x * 256 + threadIdx.x;
    if (i < n) dinv[i] = rsqrtf(1.0f + (float)counts[i]);  // +1 self loop
}

// ---------------- tiled f32 GEMM: H[n][128] = X[n][K] @ W[K][128] ----------------
template <int K>
__global__ __launch_bounds__(128) void k_gemm(const float* __restrict__ X,
                                              const float* __restrict__ W,
                                              float* __restrict__ H, int n) {
    __shared__ float As[32][68];
    __shared__ float Bs[32][132];
    const int tid = threadIdx.x;
    const int row0 = blockIdx.x * 64;
    const int ty = tid >> 4;
    const int tx = tid & 15;
    float acc[8][8] = {};
    for (int k0 = 0; k0 < K; k0 += 32) {
#pragma unroll
        for (int i = 0; i < 4; ++i) {
            int f = tid + i * 128;
            int r = f >> 3, k4 = f & 7;
            float4 v = make_float4(0.f, 0.f, 0.f, 0.f);
            if (row0 + r < n)
                v = *(const float4*)&X[(size_t)(row0 + r) * K + k0 + k4 * 4];
            As[k4 * 4 + 0][r] = v.x;
            As[k4 * 4 + 1][r] = v.y;
            As[k4 * 4 + 2][r] = v.z;
            As[k4 * 4 + 3][r] = v.w;
        }
#pragma unroll
        for (int i = 0; i < 8; ++i) {
            int f = tid + i * 128;
            int kk = f >> 5, c4 = f & 31;
            *(float4*)&Bs[kk][c4 * 4] = *(const float4*)&W[(size_t)(k0 + kk) * 128 + c4 * 4];
        }
        __syncthreads();
#pragma unroll
        for (int k = 0; k < 32; ++k) {
            float4 a0 = *(const float4*)&As[k][ty * 8];
            float4 a1 = *(const float4*)&As[k][ty * 8 + 4];
            float4 b0 = *(const float4*)&Bs[k][tx * 8];
            float4 b1 = *(const float4*)&Bs[k][tx * 8 + 4];
            float a[8] = {a0.x, a0.y, a0.z, a0.w, a1.x, a1.y, a1.z, a1.w};
            float b[8] = {b0.x, b0.y, b0.z, b0.w, b1.x, b1.y, b1.z, b1.w};
#pragma unroll
            for (int i = 0; i < 8; ++i)
#pragma unroll
                for (int j = 0; j < 8; ++j) acc[i][j] = fmaf(a[i], b[j], acc[i][j]);
        }
        __syncthreads();
    }
#pragma unroll
    for (int i = 0; i < 8; ++i) {
        int r = row0 + ty * 8 + i;
        if (r < n) {
            *(float4*)&H[(size_t)r * 128 + tx * 8] =
                make_float4(acc[i][0], acc[i][1], acc[i][2], acc[i][3]);
            *(float4*)&H[(size_t)r * 128 + tx * 8 + 4] =
                make_float4(acc[i][4], acc[i][5], acc[i][6], acc[i][7]);
        }
    }
}

// ---------------- fused CSR aggregation + self-loop + bias + ReLU ----------------
// one 32-lane half-wave per node; lane handles float4 slice of the 128-dim row
__global__ __launch_bounds__(256) void k_agg_csr(const float* __restrict__ h,
                                                 const int* __restrict__ rowptr,
                                                 const int* __restrict__ counts,
                                                 const int* __restrict__ col,
                                                 const float* __restrict__ dinv,
                                                 const float* __restrict__ b,
                                                 float* __restrict__ out) {
    int t = blockIdx.x * 256 + threadIdx.x;
    int v = t >> 5;
    int lane = t & 31;
    if (v >= N_NODES) return;
    float dv = dinv[v];
    float4 hv = *(const float4*)&h[(size_t)v * HID + lane * 4];
    float sl = dv * dv;  // self-loop norm
    float4 acc = make_float4(hv.x * sl, hv.y * sl, hv.z * sl, hv.w * sl);
    int beg = rowptr[v];
    int cnt = counts[v];
    for (int j = 0; j < cnt; ++j) {
        int s = col[beg + j];
        float w = dinv[s] * dv;
        float4 m = *(const float4*)&h[(size_t)s * HID + lane * 4];
        acc.x = fmaf(m.x, w, acc.x);
        acc.y = fmaf(m.y, w, acc.y);
        acc.z = fmaf(m.z, w, acc.z);
        acc.w = fmaf(m.w, w, acc.w);
    }
    float4 bv = *(const float4*)&b[lane * 4];
    acc.x = fmaxf(acc.x + bv.x, 0.f);
    acc.y = fmaxf(acc.y + bv.y, 0.f);
    acc.z = fmaxf(acc.z + bv.z, 0.f);
    acc.w = fmaxf(acc.w + bv.w, 0.f);
    *(float4*)&out[(size_t)v * HID + lane * 4] = acc;
}

// ---------------- final readout ----------------
__global__ void k_final(const float* __restrict__ h, const int* __restrict__ mask,
                        const float* __restrict__ Wr, const float* __restrict__ br,
                        float* __restrict__ out) {
    int t = blockIdx.x;
    int lane = threadIdx.x;
    int node = mask[t];
    float2 hv = *(const float2*)&h[(size_t)node * HID + lane * 2];
#pragma unroll
    for (int j = 0; j < OUTD; ++j) {
        float p = hv.x * Wr[(lane * 2) * OUTD + j] + hv.y * Wr[(lane * 2 + 1) * OUTD + j];
#pragma unroll
        for (int off = 32; off > 0; off >>= 1) p += __shfl_down(p, off);
        if (lane == 0) out[t * OUTD + j] = p + br[j];
    }
}

extern "C" void kernel_launch(void* const* d_in, const int* in_sizes, int n_in,
                              void* d_out, int out_size, void* d_ws, size_t ws_size,
                              hipStream_t stream) {
    const float* x  = (const float*)d_in[0];
    const int*   ei = (const int*)d_in[1];
    const int*   tm = (const int*)d_in[2];
    const float* W1 = (const float*)d_in[3];
    const float* b1 = (const float*)d_in[4];
    const float* W2 = (const float*)d_in[5];
    const float* b2 = (const float*)d_in[6];
    const float* Wr = (const float*)d_in[7];
    const float* br = (const float*)d_in[8];
    float* out = (float*)d_out;

    const int* e_src = ei;
    const int* e_dst = ei + N_EDGES;

    char* ws = (char*)d_ws;
    float* dinv   = (float*)(ws + 0x000000);            // 200 KB
    int*   counts = (int*)  (ws + 0x040000);            // 200 KB
    int*   rowptr = (int*)  (ws + 0x080000);            // 200 KB
    int*   cursor = (int*)  (ws + 0x0C0000);            // 200 KB
    int*   col    = (int*)  (ws + 0x100000);            // 3.2 MB
    float* bufA   = (float*)(ws + 0x500000);            // 25.6 MB
    float* bufB   = (float*)(ws + 0x500000 + (size_t)N_NODES * HID * 4);

    const int NB_E   = (N_EDGES + 255) / 256;
    const int NB_N   = (N_NODES + 255) / 256;
    const int NB_AGG = (N_NODES * 32 + 255) / 256;
    const int NB_G   = (N_NODES + 63) / 64;

    // ---- CSR build (by dst) + dinv ----
    hipMemsetAsync(counts, 0, N_NODES * sizeof(int), stream);
    k_hist<<<NB_E, 256, 0, stream>>>(e_dst, counts, N_EDGES);
    k_scan<<<1, 1024, 0, stream>>>(counts, rowptr);
    hipMemcpyAsync(cursor, rowptr, N_NODES * sizeof(int), hipMemcpyDeviceToDevice, stream);
    k_fill<<<NB_E, 256, 0, stream>>>(e_src, e_dst, cursor, col, N_EDGES);
    k_dinv<<<NB_N, 256, 0, stream>>>(counts, dinv, N_NODES);

    // ---- layer 1 ----
    k_gemm<EMBED><<<NB_G, 128, 0, stream>>>(x, W1, bufA, N_NODES);
    k_agg_csr<<<NB_AGG, 256, 0, stream>>>(bufA, rowptr, counts, col, dinv, b1, bufB);

    // ---- layer 2 ----
    k_gemm<HID><<<NB_G, 128, 0, stream>>>(bufB, W2, bufA, N_NODES);
    k_agg_csr<<<NB_AGG, 256, 0, stream>>>(bufA, rowptr, counts, col, dinv, b2, bufB);

    // ---- readout ----
    k_final<<<N_TGT, 64, 0, stream>>>(bufB, tm, Wr, br, out);
}